// Round 22
// baseline (69.682 us; speedup 1.0000x reference)
//
#include <hip/hip_runtime.h>
#include <hip/hip_bf16.h>
#include <cstdint>

#define B_SZ 2048
#define T_SZ 512
#define F_SZ 64
#define BPB  1               // batch rows per block
#define TCH  128             // timesteps per period
#define NCHK (T_SZ / TCH)    // 4 periods
#define NBLK (B_SZ / BPB)    // 2048 -> 8 blocks/CU (LDS ~17.5KB)
#define NTHR 128             // wv0 scan, wv1 MFMA (loads x directly)
#define MT   (TCH / 16)      // 8 M-tiles per period
#define ZSTR 17              // zbuf row stride (16 gates + 1 pad)

#define L2E 1.4426950408889634f

typedef __attribute__((ext_vector_type(8))) short short8;
typedef __attribute__((ext_vector_type(4))) float f32x4;

__device__ __forceinline__ float fast_rcp(float x) { return __builtin_amdgcn_rcpf(x); }
__device__ __forceinline__ float exp2h(float x)    { return __builtin_amdgcn_exp2f(x); }
__device__ __forceinline__ float sigm_s(float zs)  { return fast_rcp(1.0f + exp2h(zs)); }
__device__ __forceinline__ float sigm_n(float x)   { return sigm_s(x * (-L2E)); }

__device__ __forceinline__ unsigned short f2bf(float f) {
    __hip_bfloat16 h = (__hip_bfloat16)f;   // RNE
    return *reinterpret_cast<unsigned short*>(&h);
}

template<int CTRL>
__device__ __forceinline__ float dppmv(float v) {
    return __int_as_float(__builtin_amdgcn_mov_dpp(__float_as_int(v), CTRL, 0xF, 0xF, true));
}
// row_shr:N -> lane i reads lane i-N ; row_shl:N -> lane i reads lane i+N
#define DPP_SHR6 0x116   // i-gates: src lanes 0..2 -> dst 6..8
#define DPP_SHR3 0x113   // f-gates: src lanes 3..5 -> dst 6..8
#define DPP_SHL3 0x103   // o-gates: src lanes 9..11 -> dst 6..8
// row_newbcast:N (0x150+N): broadcast row-lane N to all 16 lanes (VALU DPP)
#define DPP_NB6  0x156
#define DPP_NB7  0x157
#define DPP_NB8  0x158

__global__ __launch_bounds__(NTHR, 4) void lstm_mfma(const float* __restrict__ x,
                                                     const float* __restrict__ W,
                                                     const float* __restrict__ U,
                                                     const float* __restrict__ bias,
                                                     const float* __restrict__ Wd,
                                                     const float* __restrict__ bdp,
                                                     float* __restrict__ out) {
    // z double buffer: one batch element, TCH t-rows (+4 pad rows for branchless prefetch)
    __shared__ float zbuf[2][(TCH + 4) * ZSTR];       // 2 x 8.8 KB

    const int tid = threadIdx.x;
    const int wv  = tid >> 6;
    const int ln  = tid & 63;
    const int lr  = ln & 15;                // M row within tile / gate col
    const int lg  = ln >> 4;                // 4-group
    const size_t bb = blockIdx.x;           // batch element

    // ---- gate mapping: MFMA col n = Keras gate col (q*3+m), q=n/3, m=n%3 ----
    const int n  = lr;                      // 12 real gates + 4 pad
    const int q  = n / 3;                   // 0:i 1:f 2:g 3:o (n<12)
    const float scq = (q == 2) ? (-2.0f * L2E) : (-L2E);

    // ---- B-fragments: W stationary in VGPRs (wv1 only uses them) ----
    short8 bfrag[2];
    #pragma unroll
    for (int kt = 0; kt < 2; ++kt) {
        short8 s;
        #pragma unroll
        for (int e = 0; e < 8; ++e) {
            const int hh = e >> 2, j = e & 3;
            const int kk = kt * 32 + hh * 16 + 4 * lg + j;   // f index
            const float w = (n < 12 && wv == 1) ? W[kk * 12 + n] * scq : 0.0f;
            s[e] = (short)f2bf(w);
        }
        bfrag[kt] = s;
    }
    const float bias_s = (n < 12) ? bias[n] * scq : 0.0f;

    // ---- scan constants (wv0; lanes 16-63 duplicate element harmlessly) ----
    float u0 = 0.f, u1 = 0.f, u2 = 0.f, gA = 0.f, gB = 0.f;
    if (n < 12) {
        u0 = U[0 * 12 + n] * scq;
        u1 = U[1 * 12 + n] * scq;
        u2 = U[2 * 12 + n] * scq;
        if (q == 2) { gA = -4.0f * L2E; gB = 2.0f * L2E; }  // pre-scaled tanh
        else        { gA = 1.0f;        gB = 0.0f;       }  // sigmoid
    }
    float cs = 0.f, h0b = 0.f, h1b = 0.f, h2b = 0.f;

    auto comp = [&](float z4) {
        const float z  = fmaf(h0b, u0, fmaf(h1b, u1, fmaf(h2b, u2, z4)));
        const float r  = fast_rcp(1.0f + exp2h(z));      // ONE exp2+rcp for all gates
        const float gt = fmaf(gA, r, gB);                // sigmoid / pre-scaled tanh
        const float iV = dppmv<DPP_SHR6>(gt);            // i -> g-lanes
        const float fV = dppmv<DPP_SHR3>(gt);            // f -> g-lanes
        const float oV = dppmv<DPP_SHL3>(gt);            // o -> g-lanes
        cs = fmaf(fV, cs, iV * gt);                      // g-lanes: gt = -2*L2E*g
        const float th = fmaf(2.0f, fast_rcp(1.0f + exp2h(cs)), -1.0f);  // tanh(c)
        const float h  = oV * th;                        // h_m on lane 6+m
        h0b = dppmv<DPP_NB6>(h);                         // VALU row-broadcasts
        h1b = dppmv<DPP_NB7>(h);
        h2b = dppmv<DPP_NB8>(h);
    };

    auto scan128 = [&](const float* zb) {
        const float* zp = zb + n;
        float pf[4];
        #pragma unroll
        for (int i = 0; i < 4; ++i) pf[i] = zp[i * ZSTR];
        __builtin_amdgcn_s_setprio(1);
        #pragma unroll 4
        for (int tt = 0; tt < TCH; ++tt) {               // tt&3 static within unroll-4
            const float z4 = pf[tt & 3];
            pf[tt & 3] = zp[(tt + 4) * ZSTR];            // rows TCH..TCH+3 are pad
            comp(z4);
        }
        __builtin_amdgcn_s_setprio(0);
    };

    // ---- MFMA wave: load x directly from global into A-fragments, z -> zbuf ----
    auto mfma_period = [&](int p) {
        const int buf = p & 1;
        const float* xb = x + ((size_t)bb * T_SZ + p * TCH) * F_SZ;
        #pragma unroll
        for (int mt = 0; mt < MT; ++mt) {
            // 4 x float4: (kt,h) pairs; wave reads 16 rows x 64B contiguous
            const float* xr = xb + (size_t)(mt * 16 + lr) * F_SZ + 4 * lg;
            const float4 v00 = *reinterpret_cast<const float4*>(xr + 0);    // kt0 h0
            const float4 v01 = *reinterpret_cast<const float4*>(xr + 16);   // kt0 h1
            const float4 v10 = *reinterpret_cast<const float4*>(xr + 32);   // kt1 h0
            const float4 v11 = *reinterpret_cast<const float4*>(xr + 48);   // kt1 h1
            short8 a0, a1;
            a0[0] = (short)f2bf(v00.x); a0[1] = (short)f2bf(v00.y);
            a0[2] = (short)f2bf(v00.z); a0[3] = (short)f2bf(v00.w);
            a0[4] = (short)f2bf(v01.x); a0[5] = (short)f2bf(v01.y);
            a0[6] = (short)f2bf(v01.z); a0[7] = (short)f2bf(v01.w);
            a1[0] = (short)f2bf(v10.x); a1[1] = (short)f2bf(v10.y);
            a1[2] = (short)f2bf(v10.z); a1[3] = (short)f2bf(v10.w);
            a1[4] = (short)f2bf(v11.x); a1[5] = (short)f2bf(v11.y);
            a1[6] = (short)f2bf(v11.z); a1[7] = (short)f2bf(v11.w);
            f32x4 acc = { bias_s, bias_s, bias_s, bias_s };
            acc = __builtin_amdgcn_mfma_f32_16x16x32_bf16(a0, bfrag[0], acc, 0, 0, 0);
            acc = __builtin_amdgcn_mfma_f32_16x16x32_bf16(a1, bfrag[1], acc, 0, 0, 0);
            #pragma unroll
            for (int r = 0; r < 4; ++r) {
                const int t = mt * 16 + 4 * lg + r;      // C row = t ; col = gate
                zbuf[buf][t * ZSTR + lr] = acc[r];
            }
        }
    };

    // ---- pipeline: mfma z(p) || scan z(p-1), one barrier per period ----
    for (int p = 0; p < NCHK; ++p) {
        if (wv == 1) mfma_period(p);
        else if (p > 0) scan128(zbuf[(p - 1) & 1]);
        __syncthreads();
    }

    // ---- epilogue: scan last period + dense head ----
    if (wv == 0) {
        scan128(zbuf[(NCHK - 1) & 1]);
        if (ln == 0) {
            const float logit = bdp[0] + h0b * Wd[0] + h1b * Wd[1] + h2b * Wd[2];
            out[bb] = sigm_n(logit);
        }
    }
}

extern "C" void kernel_launch(void* const* d_in, const int* in_sizes, int n_in,
                              void* d_out, int out_size, void* d_ws, size_t ws_size,
                              hipStream_t stream) {
    (void)in_sizes; (void)n_in; (void)out_size; (void)d_ws; (void)ws_size;
    const float* x  = (const float*)d_in[0];
    const float* W  = (const float*)d_in[1];
    const float* U  = (const float*)d_in[2];
    const float* b  = (const float*)d_in[3];
    const float* Wd = (const float*)d_in[4];
    const float* bd = (const float*)d_in[5];
    float* out = (float*)d_out;

    lstm_mfma<<<NBLK, NTHR, 0, stream>>>(x, W, U, b, Wd, bd, out);
}